// Round 1
// baseline (277.553 us; speedup 1.0000x reference)
//
#include <hip/hip_runtime.h>

#define B_ 32
#define T_ 2048
#define D_ 512

// ---------------- K1: energy[b,t] = dot(key[b,t,:], q[b,:]) ----------------
// One wave per (b,t). 512 blocks per batch (4 waves/block, 2048 t / batch).
__global__ __launch_bounds__(256) void energy_kernel(
    const float* __restrict__ q,
    const float* __restrict__ key,
    float* __restrict__ energy)
{
    __shared__ float4 qs[128];                 // q[b] staged: 512 floats
    const int b = blockIdx.x >> 9;             // 512 blocks per batch
    if (threadIdx.x < 128)
        qs[threadIdx.x] = ((const float4*)q)[b * 128 + threadIdx.x];
    __syncthreads();

    const int wave = threadIdx.x >> 6;
    const int lane = threadIdx.x & 63;
    const int gw   = blockIdx.x * 4 + wave;    // global wave id = b*T + t
    const int t    = gw & (T_ - 1);

    const float4* k4 = (const float4*)key + (size_t)(b * T_ + t) * (D_ / 4);
    float acc = 0.f;
#pragma unroll
    for (int j = 0; j < 2; ++j) {
        float4 kv = k4[j * 64 + lane];
        float4 qv = qs[j * 64 + lane];
        acc += kv.x * qv.x + kv.y * qv.y + kv.z * qv.z + kv.w * qv.w;
    }
#pragma unroll
    for (int off = 32; off >= 1; off >>= 1)
        acc += __shfl_down(acc, off);
    if (lane == 0)
        energy[gw] = acc;
}

// ---------------- K2: softmax over T per batch, write attention ----------------
__global__ __launch_bounds__(256) void softmax_kernel(
    const float* __restrict__ energy,
    float* __restrict__ attn)                  // [B, T] region of d_out
{
    const int b = blockIdx.x;
    const int wave = threadIdx.x >> 6;
    const int lane = threadIdx.x & 63;

    const float4* e4 = (const float4*)(energy + b * T_);
    float4 v0 = e4[threadIdx.x * 2 + 0];
    float4 v1 = e4[threadIdx.x * 2 + 1];

    // ---- block max ----
    float m = fmaxf(fmaxf(fmaxf(v0.x, v0.y), fmaxf(v0.z, v0.w)),
                    fmaxf(fmaxf(v1.x, v1.y), fmaxf(v1.z, v1.w)));
#pragma unroll
    for (int off = 32; off >= 1; off >>= 1)
        m = fmaxf(m, __shfl_xor(m, off));
    __shared__ float redm[4];
    if (lane == 0) redm[wave] = m;
    __syncthreads();
    m = fmaxf(fmaxf(redm[0], redm[1]), fmaxf(redm[2], redm[3]));

    // ---- exp + block sum ----
    float4 x0, x1;
    x0.x = expf(v0.x - m); x0.y = expf(v0.y - m);
    x0.z = expf(v0.z - m); x0.w = expf(v0.w - m);
    x1.x = expf(v1.x - m); x1.y = expf(v1.y - m);
    x1.z = expf(v1.z - m); x1.w = expf(v1.w - m);
    float s = x0.x + x0.y + x0.z + x0.w + x1.x + x1.y + x1.z + x1.w;
#pragma unroll
    for (int off = 32; off >= 1; off >>= 1)
        s += __shfl_xor(s, off);
    __shared__ float reds[4];
    if (lane == 0) reds[wave] = s;
    __syncthreads();
    s = reds[0] + reds[1] + reds[2] + reds[3];

    const float inv = 1.f / s;
    x0.x *= inv; x0.y *= inv; x0.z *= inv; x0.w *= inv;
    x1.x *= inv; x1.y *= inv; x1.z *= inv; x1.w *= inv;

    float4* a4 = (float4*)(attn + b * T_);
    a4[threadIdx.x * 2 + 0] = x0;
    a4[threadIdx.x * 2 + 1] = x1;
}

// ---------------- K3: partial[b,chunk,:] = sum_{t in chunk} attn[b,t] * value[b,t,:] ----------------
// 256 blocks = 32 b x 8 chunks (256 t each). 512 threads: 4 row-groups x 128 float4 d-slices.
__global__ __launch_bounds__(512) void context_partial_kernel(
    const float* __restrict__ attn,
    const float* __restrict__ value,
    float* __restrict__ partial)               // [B, 8, D]
{
    __shared__ float  attn_s[256];
    __shared__ float4 red4[512];               // 4 groups x 128 float4

    const int b     = blockIdx.x >> 3;
    const int chunk = blockIdx.x & 7;
    const int t0    = chunk * 256;

    if (threadIdx.x < 256)
        attn_s[threadIdx.x] = attn[b * T_ + t0 + threadIdx.x];
    __syncthreads();

    const int tg = threadIdx.x >> 7;           // row group 0..3
    const int d4 = threadIdx.x & 127;          // float4 index in D

    const float4* v4 = (const float4*)value + (size_t)(b * T_ + t0 + tg) * (D_ / 4) + d4;
    float4 acc = {0.f, 0.f, 0.f, 0.f};
#pragma unroll 8
    for (int i = 0; i < 64; ++i) {             // t = t0 + 4*i + tg
        const float a = attn_s[4 * i + tg];
        const float4 vv = v4[i * 4 * (D_ / 4)];
        acc.x += a * vv.x; acc.y += a * vv.y;
        acc.z += a * vv.z; acc.w += a * vv.w;
    }

    red4[tg * 128 + d4] = acc;
    __syncthreads();
    if (threadIdx.x < 128) {
        float4 a0 = red4[threadIdx.x +   0];
        float4 a1 = red4[threadIdx.x + 128];
        float4 a2 = red4[threadIdx.x + 256];
        float4 a3 = red4[threadIdx.x + 384];
        float4 sv;
        sv.x = a0.x + a1.x + a2.x + a3.x;
        sv.y = a0.y + a1.y + a2.y + a3.y;
        sv.z = a0.z + a1.z + a2.z + a3.z;
        sv.w = a0.w + a1.w + a2.w + a3.w;
        ((float4*)partial)[(b * 8 + chunk) * 128 + threadIdx.x] = sv;
    }
}

// ---------------- K4: out[b,:] = sum over 8 chunk partials ----------------
__global__ __launch_bounds__(128) void reduce_kernel(
    const float* __restrict__ partial,
    float* __restrict__ out)
{
    const int b  = blockIdx.x;
    const int d4 = threadIdx.x;
    float4 s = {0.f, 0.f, 0.f, 0.f};
#pragma unroll
    for (int c = 0; c < 8; ++c) {
        float4 p = ((const float4*)partial)[(b * 8 + c) * 128 + d4];
        s.x += p.x; s.y += p.y; s.z += p.z; s.w += p.w;
    }
    ((float4*)out)[b * 128 + d4] = s;
}

extern "C" void kernel_launch(void* const* d_in, const int* in_sizes, int n_in,
                              void* d_out, int out_size, void* d_ws, size_t ws_size,
                              hipStream_t stream)
{
    const float* q     = (const float*)d_in[0];   // [B, D]
    const float* key   = (const float*)d_in[1];   // [B, T, D]
    const float* value = (const float*)d_in[2];   // [B, T, D]

    float* out  = (float*)d_out;                  // [B, D] first
    float* attn = out + B_ * D_;                  // [B, T] second

    float* energy  = (float*)d_ws;                // B*T floats   (256 KiB)
    float* partial = energy + B_ * T_;            // B*8*D floats (512 KiB)

    energy_kernel<<<B_ * T_ / 4, 256, 0, stream>>>(q, key, energy);
    softmax_kernel<<<B_, 256, 0, stream>>>(energy, attn);
    context_partial_kernel<<<B_ * 8, 512, 0, stream>>>(attn, value, partial);
    reduce_kernel<<<B_, 128, 0, stream>>>(partial, out);
}